// Round 10
// baseline (458.332 us; speedup 1.0000x reference)
//
#include <hip/hip_runtime.h>
#include <hip/hip_bf16.h>
#include <string.h>

#define NN   4096
#define NE   32768
#define NB   32
#define BKT  64   // per-src edge bucket capacity (deg ~ Poisson(8); P(>64) ~ 1e-30)
#define FN   8    // src nodes per fused block (Plds = 8*64*64*2B = 64 KB)

typedef __attribute__((ext_vector_type(8))) short short8;
typedef __attribute__((ext_vector_type(4))) float f4;

__device__ __forceinline__ float sigf(float x) { return 1.0f / (1.0f + __expf(-x)); }
__device__ __forceinline__ short f2bf(float f) {
    __hip_bfloat16 h = __float2bfloat16(f);
    short s;
    memcpy(&s, &h, sizeof(short));
    return s;
}
__device__ __forceinline__ unsigned packbf2(float lo, float hi) {
    return (unsigned)(unsigned short)f2bf(lo) | ((unsigned)(unsigned short)f2bf(hi) << 16);
}

// ---------------- k_setup: init + W2T transpose + pre-MLP (+BT0 +agg zero) ----------
// blocks 0..31: zero counters, init batch ranges
// blocks 32..223: enn_W2[l][g][k][o] -> W2T[(l*64+g)][o][k] bf16
// blocks 224..1247: pre-MLP (4 nodes/block) + BT0 = out.b2_0 + zero agg
__global__ __launch_bounds__(256) void k_setup(const float* __restrict__ x,
        const float* __restrict__ W0, const float* __restrict__ b0,
        const float* __restrict__ W1, const float* __restrict__ b1,
        const float* __restrict__ W2, const float* __restrict__ b2,
        const float* __restrict__ enn_W2, const float* __restrict__ b2e0,
        __hip_bfloat16* __restrict__ W2T, float* __restrict__ out,
        float* __restrict__ BT, float* __restrict__ agg,
        int* cnt_src, int* cnt_dst, int* bstart, int* bend) {
    int bid = blockIdx.x, t = threadIdx.x;
    if (bid < 32) {
        int i = bid * 256 + t;
        if (i < NN) cnt_src[i] = 0;
        else cnt_dst[i - NN] = 0;
        if (i < NB) { bstart[i] = 0x7FFFFFFF; bend[i] = 0; }
    } else if (bid < 224) {
        __shared__ __hip_bfloat16 tile[64 * 65];
        size_t base = (size_t)(bid - 32) * 4096;
        for (int i = t; i < 4096; i += 256) {
            int k = i >> 6, o = i & 63;
            tile[o * 65 + k] = __float2bfloat16(enn_W2[base + i]);
        }
        __syncthreads();
        for (int i = t; i < 4096; i += 256) {
            int o = i >> 6, k = i & 63;
            W2T[base + i] = tile[o * 65 + k];
        }
    } else {
        __shared__ float xr[4][128], ha[4][64], hb[4][64];
        int w = t >> 6, j = t & 63;
        int n = (bid - 224) * 4 + w;
        xr[w][j] = x[(size_t)n * 128 + j];
        xr[w][64 + j] = x[(size_t)n * 128 + 64 + j];
        float s = b0[j];
        #pragma unroll 8
        for (int k = 0; k < 128; ++k) s = fmaf(xr[w][k], W0[k * 64 + j], s);
        ha[w][j] = fmaxf(s, 0.f);
        s = b1[j];
        #pragma unroll 8
        for (int k = 0; k < 64; ++k) s = fmaf(ha[w][k], W1[k * 64 + j], s);
        hb[w][j] = fmaxf(s, 0.f);
        s = b2[j];
        #pragma unroll 8
        for (int k = 0; k < 64; ++k) s = fmaf(hb[w][k], W2[k * 64 + j], s);
        float val = fmaxf(s, 0.f);
        out[(size_t)n * 64 + j] = val;
        ha[w][j] = val;             // wave-private reuse (all ha reads above are done)
        agg[(size_t)n * 64 + j] = 0.f;
        float s2 = 0.f;
        #pragma unroll 8
        for (int k = 0; k < 64; ++k) s2 = fmaf(ha[w][k], b2e0[k * 64 + j], s2);
        BT[(size_t)n * 64 + j] = s2;
    }
}

// ---------------- k_edges: bucket CSR fill + cnt_dst + batch ranges ----------------
__global__ __launch_bounds__(256) void k_edges(const int* __restrict__ eidx,
        const float* __restrict__ ea, const int* __restrict__ bm,
        int* cnt_src, int* cnt_dst, int* csr_dst, float* csr_ea,
        int* bstart, int* bend) {
    int e = blockIdx.x * 256 + threadIdx.x;
    if (e < NE) {
        int s = eidx[e];
        int d = eidx[NE + e];
        int slot = atomicAdd(&cnt_src[s], 1);
        if (slot < BKT) {
            csr_dst[s * BKT + slot] = d;
            csr_ea[s * BKT + slot] = ea[e];
        }
        atomicAdd(&cnt_dst[d], 1);
    }
    if (e < NN) {
        int b = bm[e];
        atomicMin(&bstart[b], e);
        atomicMax(&bend[b], e + 1);
    }
}

// ---------------- k_fused: P-tile MFMA into LDS + edge message + scatter ----------
// Block = 8 src nodes. Phase 1: P[8n][64g][64o] = out@W2 via MFMA (16-row tiles,
// rows 8..15 computed-and-discarded), stored to LDS packed as u32 = (bf16 g0, bf16 g1).
// Phase 2 (after one barrier): per edge, msg[o=lane] = BT + sum_g We1[g]*P[n][g][o],
// We1 broadcast from a lane=g register via __shfl (readlane). No P in global memory.
__global__ __launch_bounds__(256, 2) void k_fused(const float* __restrict__ out,
        const __hip_bfloat16* __restrict__ W2T_l, const float* __restrict__ BT,
        const int* __restrict__ cnt_src, const int* __restrict__ csr_dst,
        const float* __restrict__ csr_ea, const float* __restrict__ W1l,
        const float* __restrict__ b1l, float* __restrict__ agg) {
    __shared__ unsigned Plds[FN * 32 * 64];   // [n][g2][o], 2 bf16/word = 64 KB exactly
    int t = threadIdx.x, wave = t >> 6, lane = t & 63;
    int laneM = lane & 15, quad = lane >> 4;
    int n0 = blockIdx.x * FN;
    // A-fragment: A[m=laneM][k=quad*8+j] direct from global (rows 8..15 discarded;
    // reads stay inside workspace for the last block)
    const float* Arow = out + (size_t)(n0 + laneM) * 64;
    f4 af0 = *(const f4*)(Arow + quad * 8);
    f4 af1 = *(const f4*)(Arow + quad * 8 + 4);
    f4 af2 = *(const f4*)(Arow + 32 + quad * 8);
    f4 af3 = *(const f4*)(Arow + 32 + quad * 8 + 4);
    short8 a0, a1;
    #pragma unroll
    for (int j = 0; j < 4; ++j) {
        a0[j] = f2bf(af0[j]); a0[4 + j] = f2bf(af1[j]);
        a1[j] = f2bf(af2[j]); a1[4 + j] = f2bf(af3[j]);
    }
    // wave w covers g in [16w, 16w+16), as 8 even/odd pairs
    #pragma unroll
    for (int gp = 0; gp < 8; ++gp) {
        int g0 = wave * 16 + gp * 2;
        const __hip_bfloat16* Bt0 = W2T_l + (size_t)g0 * 4096;   // [o][k]
        const __hip_bfloat16* Bt1 = Bt0 + 4096;
        #pragma unroll
        for (int ot = 0; ot < 4; ++ot) {
            int o0 = ot * 16;
            short8 b00 = *(const short8*)(Bt0 + (o0 + laneM) * 64 + quad * 8);
            short8 b01 = *(const short8*)(Bt0 + (o0 + laneM) * 64 + 32 + quad * 8);
            short8 b10 = *(const short8*)(Bt1 + (o0 + laneM) * 64 + quad * 8);
            short8 b11 = *(const short8*)(Bt1 + (o0 + laneM) * 64 + 32 + quad * 8);
            f4 c0 = {0.f, 0.f, 0.f, 0.f};
            f4 c1 = {0.f, 0.f, 0.f, 0.f};
            c0 = __builtin_amdgcn_mfma_f32_16x16x32_bf16(a0, b00, c0, 0, 0, 0);
            c0 = __builtin_amdgcn_mfma_f32_16x16x32_bf16(a1, b01, c0, 0, 0, 0);
            c1 = __builtin_amdgcn_mfma_f32_16x16x32_bf16(a0, b10, c1, 0, 0, 0);
            c1 = __builtin_amdgcn_mfma_f32_16x16x32_bf16(a1, b11, c1, 0, 0, 0);
            // C: col(o)=lane&15, row(node)=quad*4+r; keep nodes 0..7 only
            if (quad < 2) {
                #pragma unroll
                for (int r = 0; r < 4; ++r) {
                    int node = quad * 4 + r;
                    Plds[(node * 32 + (g0 >> 1)) * 64 + o0 + laneM] = packbf2(c0[r], c1[r]);
                }
            }
        }
    }
    __syncthreads();
    // edge phase: wave handles nodes 2w, 2w+1
    float wcoef = W1l[lane], bcoef = b1l[lane];
    #pragma unroll
    for (int ni = 0; ni < 2; ++ni) {
        int nloc = wave * 2 + ni;
        int n = n0 + nloc;
        int deg = cnt_src[n];
        if (deg > BKT) deg = BKT;
        float bt = BT[(size_t)n * 64 + lane];
        const int* bdst = csr_dst + n * BKT;
        const float* bea = csr_ea + n * BKT;
        const unsigned* Pn = Plds + nloc * 2048;
        for (int i = 0; i < deg; ++i) {
            float eav = bea[i];
            int dst = bdst[i];
            float we = fmaxf(fmaf(eav, wcoef, bcoef), 0.f);   // lane = g
            float acc = bt;
            #pragma unroll
            for (int g2 = 0; g2 < 32; ++g2) {
                unsigned pv = Pn[g2 * 64 + lane];
                union { unsigned u; float f; } lo, hi;
                lo.u = pv << 16;            // g = 2*g2
                hi.u = pv & 0xFFFF0000u;    // g = 2*g2+1
                float w0 = __shfl(we, g2 * 2, 64);
                float w1 = __shfl(we, g2 * 2 + 1, 64);
                acc = fmaf(w0, lo.f, acc);
                acc = fmaf(w1, hi.f, acc);
            }
            atomicAdd(&agg[(size_t)dst * 64 + lane], acc);   // un-normalized; /deg in GRU
        }
    }
}

// ---------------- k_gru: conv (+deg-norm) + GRU (+BT_next +agg zero) ----------------
__global__ __launch_bounds__(256) void k_gru(const float* __restrict__ out,
        const float* __restrict__ agg, const int* __restrict__ cnt_dst,
        const float* __restrict__ rootW, const float* __restrict__ convb,
        const float* __restrict__ Wih, const float* __restrict__ Whh,
        const float* __restrict__ bih, const float* __restrict__ bhh,
        const float* __restrict__ b2next, float* __restrict__ BT,
        float* __restrict__ aggz, float* __restrict__ outn) {
    __shared__ float sh[4][64], sc[4][64];
    int t = threadIdx.x, w = t >> 6, j = t & 63;
    int n = blockIdx.x * 4 + w;
    float hj = out[(size_t)n * 64 + j];
    sh[w][j] = hj;
    int dg = cnt_dst[n];
    float invd = 1.0f / (float)(dg > 0 ? dg : 1);
    __syncthreads();
    float s = agg[(size_t)n * 64 + j] * invd + convb[j];
    #pragma unroll 8
    for (int k = 0; k < 64; ++k) s = fmaf(sh[w][k], rootW[k * 64 + j], s);
    float conv = fmaxf(s, 0.f);
    sc[w][j] = conv;
    __syncthreads();
    float gir = bih[j], giz = bih[64 + j], gin = bih[128 + j];
    float ghr = bhh[j], ghz = bhh[64 + j], ghn = bhh[128 + j];
    #pragma unroll 4
    for (int k = 0; k < 64; ++k) {
        float c = sc[w][k], h = sh[w][k];
        gir = fmaf(c, Wih[k * 192 + j], gir);
        giz = fmaf(c, Wih[k * 192 + 64 + j], giz);
        gin = fmaf(c, Wih[k * 192 + 128 + j], gin);
        ghr = fmaf(h, Whh[k * 192 + j], ghr);
        ghz = fmaf(h, Whh[k * 192 + 64 + j], ghz);
        ghn = fmaf(h, Whh[k * 192 + 128 + j], ghn);
    }
    float r = sigf(gir + ghr);
    float z = sigf(giz + ghz);
    float nnv = tanhf(gin + r * ghn);
    float val = (1.f - z) * nnv + z * hj;
    outn[(size_t)n * 64 + j] = val;
    if (b2next) {
        sh[w][j] = val;   // wave-private reuse (all sh reads above done in lockstep)
        aggz[(size_t)n * 64 + j] = 0.f;
        float s2 = 0.f;
        #pragma unroll 8
        for (int k = 0; k < 64; ++k) s2 = fmaf(sh[w][k], b2next[k * 64 + j], s2);
        BT[(size_t)n * 64 + j] = s2;
    }
}

// ---------------- Set2Set (3 steps) + post-MLP ----------------
__global__ __launch_bounds__(1024) void k_s2s_post(const float* __restrict__ out,
        const int* __restrict__ bstart, const int* __restrict__ bend,
        const float* __restrict__ Wih, const float* __restrict__ Whh,
        const float* __restrict__ bih, const float* __restrict__ bhh,
        const float* __restrict__ pW0, const float* __restrict__ pb0,
        const float* __restrict__ pW1, const float* __restrict__ pb1,
        const float* __restrict__ pW2, const float* __restrict__ pb2,
        const float* __restrict__ pW3, const float* __restrict__ pb3,
        float* __restrict__ y) {
    __shared__ float cache[192 * 65];
    __shared__ float qs[128], hh[64], cc[64], gates[256];
    __shared__ float ebuf[1024];
    __shared__ float redbuf[1024];
    __shared__ float redw[16];
    __shared__ float smax, sinv;
    __shared__ float tmp64[64];
    int t = threadIdx.x, wave = t >> 6, lane = t & 63;
    int b = blockIdx.x;
    int s0 = bstart[b], e0 = bend[b];
    int cnt = e0 - s0;
    if (cnt < 0) cnt = 0;
    if (cnt > 1024) cnt = 1024;
    int ccnt = cnt < 192 ? cnt : 192;
    for (int li = t; li < ccnt * 64; li += 1024) {
        int rowi = li >> 6, d = li & 63;
        cache[rowi * 65 + d] = out[(size_t)(s0 + rowi) * 64 + d];
    }
    int g = t & 255, seg = t >> 8;
    const float* wp;
    int kcnt;
    if (seg == 0)      { wp = Wih + g;             kcnt = 64; }
    else if (seg == 1) { wp = Wih + 64 * 256 + g;  kcnt = 64; }
    else if (seg == 2) { wp = Whh + g;             kcnt = 32; }
    else               { wp = Whh + 32 * 256 + g;  kcnt = 32; }
    float wreg[64];
    #pragma unroll
    for (int j = 0; j < 64; ++j)
        wreg[j] = (j < kcnt) ? wp[(size_t)j * 256] : 0.f;
    if (t < 128) qs[t] = 0.f;
    if (t < 64) { hh[t] = 0.f; cc[t] = 0.f; }
    __syncthreads();
    for (int step = 0; step < 3; ++step) {
        const float* vsrc = (seg == 0) ? qs : (seg == 1) ? qs + 64
                          : (seg == 2) ? hh : hh + 32;
        float partial = 0.f;
        #pragma unroll
        for (int j = 0; j < 64; ++j)
            if (j < kcnt) partial = fmaf(vsrc[j], wreg[j], partial);
        redbuf[seg * 256 + g] = partial;
        __syncthreads();
        if (t < 256)
            gates[t] = bih[t] + bhh[t] + redbuf[t] + redbuf[256 + t]
                     + redbuf[512 + t] + redbuf[768 + t];
        __syncthreads();
        if (t < 64) {
            float cn = sigf(gates[64 + t]) * cc[t] + sigf(gates[t]) * tanhf(gates[128 + t]);
            cc[t] = cn;
            hh[t] = sigf(gates[192 + t]) * tanhf(cn);
        }
        __syncthreads();
        for (int idx = t; idx < cnt; idx += 1024) {
            float s = 0.f;
            if (idx < 192) {
                const float* row = cache + idx * 65;
                #pragma unroll 8
                for (int d = 0; d < 64; ++d) s = fmaf(row[d], hh[d], s);
            } else {
                const float* row = out + (size_t)(s0 + idx) * 64;
                for (int d = 0; d < 64; ++d) s = fmaf(row[d], hh[d], s);
            }
            ebuf[idx] = s;
        }
        __syncthreads();
        float lm = (t < cnt) ? ebuf[t] : -3.0e38f;
        #pragma unroll
        for (int off = 32; off > 0; off >>= 1) lm = fmaxf(lm, __shfl_down(lm, off, 64));
        if (lane == 0) redw[wave] = lm;
        __syncthreads();
        if (t == 0) {
            float m = redw[0];
            #pragma unroll
            for (int w2 = 1; w2 < 16; ++w2) m = fmaxf(m, redw[w2]);
            smax = m;
        }
        __syncthreads();
        float m = smax;
        float av = 0.f;
        if (t < cnt) {
            av = __expf(ebuf[t] - m);
            ebuf[t] = av;
        }
        float ls = av;
        #pragma unroll
        for (int off = 32; off > 0; off >>= 1) ls += __shfl_down(ls, off, 64);
        if (lane == 0) redw[wave] = ls;
        __syncthreads();
        if (t == 0) {
            float s = 0.f;
            #pragma unroll
            for (int w2 = 0; w2 < 16; ++w2) s += redw[w2];
            sinv = (cnt > 0) ? 1.f / s : 0.f;
        }
        __syncthreads();
        float inv = sinv;
        float r = 0.f;
        for (int idx = wave; idx < cnt; idx += 16) {
            float a = ebuf[idx];
            float v = (idx < 192) ? cache[idx * 65 + lane]
                                  : out[(size_t)(s0 + idx) * 64 + lane];
            r = fmaf(a, v, r);
        }
        redbuf[wave * 64 + lane] = r;
        __syncthreads();
        if (t < 64) {
            float s = 0.f;
            #pragma unroll
            for (int w2 = 0; w2 < 16; ++w2) s += redbuf[w2 * 64 + t];
            qs[64 + t] = s * inv;
            qs[t] = hh[t];
        }
        __syncthreads();
    }
    if (t < 64) {
        float s = pb0[t];
        #pragma unroll 4
        for (int k = 0; k < 128; ++k) s = fmaf(qs[k], pW0[k * 64 + t], s);
        tmp64[t] = fmaxf(s, 0.f);
    }
    __syncthreads();
    float h1v = 0.f;
    if (t < 64) {
        float s = pb1[t];
        #pragma unroll 4
        for (int k = 0; k < 64; ++k) s = fmaf(tmp64[k], pW1[k * 64 + t], s);
        h1v = fmaxf(s, 0.f);
    }
    __syncthreads();
    if (t < 64) tmp64[t] = h1v;
    __syncthreads();
    if (t < 64) {
        float s = pb2[t];
        #pragma unroll 4
        for (int k = 0; k < 64; ++k) s = fmaf(tmp64[k], pW2[k * 64 + t], s);
        gates[t] = fmaxf(s, 0.f) * pW3[t];
    }
    __syncthreads();
    if (t == 0) {
        float yy = pb3[0];
        for (int k = 0; k < 64; ++k) yy += gates[k];
        y[b] = yy;
    }
}

// ---------------- host ----------------

extern "C" void kernel_launch(void* const* d_in, const int* in_sizes, int n_in,
                              void* d_out, int out_size, void* d_ws, size_t ws_size,
                              hipStream_t stream) {
    const float* x         = (const float*)d_in[0];
    const float* edge_attr = (const float*)d_in[1];
    const int*   edge_idx  = (const int*)d_in[2];
    const int*   batch_map = (const int*)d_in[3];
    const float* pre_W0 = (const float*)d_in[4];
    const float* pre_b0 = (const float*)d_in[5];
    const float* pre_W1 = (const float*)d_in[6];
    const float* pre_b1 = (const float*)d_in[7];
    const float* pre_W2 = (const float*)d_in[8];
    const float* pre_b2 = (const float*)d_in[9];
    const float* enn_W1 = (const float*)d_in[10];
    const float* enn_b1 = (const float*)d_in[11];
    const float* enn_W2 = (const float*)d_in[12];
    const float* enn_b2 = (const float*)d_in[13];
    const float* root_W = (const float*)d_in[14];
    const float* conv_b = (const float*)d_in[15];
    const float* gru_Wih = (const float*)d_in[16];
    const float* gru_Whh = (const float*)d_in[17];
    const float* gru_bih = (const float*)d_in[18];
    const float* gru_bhh = (const float*)d_in[19];
    const float* s2s_Wih = (const float*)d_in[20];
    const float* s2s_Whh = (const float*)d_in[21];
    const float* s2s_bih = (const float*)d_in[22];
    const float* s2s_bhh = (const float*)d_in[23];
    const float* post_W0 = (const float*)d_in[24];
    const float* post_b0 = (const float*)d_in[25];
    const float* post_W1 = (const float*)d_in[26];
    const float* post_b1 = (const float*)d_in[27];
    const float* post_W2 = (const float*)d_in[28];
    const float* post_b2 = (const float*)d_in[29];
    const float* post_W3 = (const float*)d_in[30];
    const float* post_b3 = (const float*)d_in[31];
    float* yout = (float*)d_out;

    char* wp = (char*)d_ws;
    auto take = [&](size_t bytes) -> char* {
        char* r = wp;
        wp += (bytes + 255) & ~(size_t)255;
        return r;
    };
    float* outA = (float*)take((size_t)NN * 64 * 4);
    float* outB = (float*)take((size_t)NN * 64 * 4);
    float* BT  = (float*)take((size_t)NN * 64 * 4);
    float* agg = (float*)take((size_t)NN * 64 * 4);
    __hip_bfloat16* W2T = (__hip_bfloat16*)take((size_t)3 * 64 * 4096 * 2);
    int* cnt_src  = (int*)take((size_t)NN * 4);
    int* cnt_dst  = (int*)take((size_t)NN * 4);
    int* csr_dst  = (int*)take((size_t)NN * BKT * 4);
    float* csr_ea = (float*)take((size_t)NN * BKT * 4);
    int* bstart   = (int*)take((size_t)NB * 4);
    int* bend     = (int*)take((size_t)NB * 4);

    k_setup<<<1248, 256, 0, stream>>>(x, pre_W0, pre_b0, pre_W1, pre_b1, pre_W2, pre_b2,
                                      enn_W2, enn_b2, W2T, outA, BT, agg,
                                      cnt_src, cnt_dst, bstart, bend);
    k_edges<<<NE / 256, 256, 0, stream>>>(edge_idx, edge_attr, batch_map,
                                          cnt_src, cnt_dst, csr_dst, csr_ea,
                                          bstart, bend);

    float* cur = outA;
    float* nxt = outB;
    for (int l = 0; l < 3; ++l) {
        k_fused<<<NN / FN, 256, 0, stream>>>(cur, W2T + (size_t)l * 64 * 4096, BT,
                                             cnt_src, csr_dst, csr_ea,
                                             enn_W1 + l * 64, enn_b1 + l * 64, agg);
        const float* b2next = (l < 2) ? (enn_b2 + (size_t)(l + 1) * 4096) : nullptr;
        k_gru<<<NN / 4, 256, 0, stream>>>(cur, agg, cnt_dst, root_W + l * 4096,
                                          conv_b + l * 64, gru_Wih + l * 64 * 192,
                                          gru_Whh + l * 64 * 192, gru_bih + l * 192,
                                          gru_bhh + l * 192, b2next, BT, agg, nxt);
        float* tmp = cur; cur = nxt; nxt = tmp;
    }
    k_s2s_post<<<NB, 1024, 0, stream>>>(cur, bstart, bend, s2s_Wih, s2s_Whh, s2s_bih,
                                        s2s_bhh, post_W0, post_b0, post_W1, post_b1,
                                        post_W2, post_b2, post_W3, post_b3, yout);
}

// Round 11
// 400.307 us; speedup vs baseline: 1.1450x; 1.1450x over previous
//
#include <hip/hip_runtime.h>
#include <hip/hip_bf16.h>
#include <string.h>

#define NN   4096
#define NE   32768
#define NB   32
#define BKT  64   // per-src edge bucket capacity (deg ~ Poisson(8); P(>64) ~ 1e-30)
#define FN   8    // src nodes per fused block (Plds = 8*64*64*2B = 64 KB)

typedef __attribute__((ext_vector_type(8))) short short8;
typedef __attribute__((ext_vector_type(4))) float f4;

__device__ __forceinline__ float sigf(float x) { return 1.0f / (1.0f + __expf(-x)); }
__device__ __forceinline__ short f2bf(float f) {
    __hip_bfloat16 h = __float2bfloat16(f);
    short s;
    memcpy(&s, &h, sizeof(short));
    return s;
}
__device__ __forceinline__ unsigned packbf2(float lo, float hi) {
    return (unsigned)(unsigned short)f2bf(lo) | ((unsigned)(unsigned short)f2bf(hi) << 16);
}

// ---------------- k_setup: init + W2T transpose + pre-MLP (+BT0 +agg zero) ----------
__global__ __launch_bounds__(256) void k_setup(const float* __restrict__ x,
        const float* __restrict__ W0, const float* __restrict__ b0,
        const float* __restrict__ W1, const float* __restrict__ b1,
        const float* __restrict__ W2, const float* __restrict__ b2,
        const float* __restrict__ enn_W2, const float* __restrict__ b2e0,
        __hip_bfloat16* __restrict__ W2T, float* __restrict__ out,
        float* __restrict__ BT, float* __restrict__ agg,
        int* cnt_src, int* cnt_dst, int* bstart, int* bend) {
    int bid = blockIdx.x, t = threadIdx.x;
    if (bid < 32) {
        int i = bid * 256 + t;
        if (i < NN) cnt_src[i] = 0;
        else cnt_dst[i - NN] = 0;
        if (i < NB) { bstart[i] = 0x7FFFFFFF; bend[i] = 0; }
    } else if (bid < 224) {
        __shared__ __hip_bfloat16 tile[64 * 65];
        size_t base = (size_t)(bid - 32) * 4096;
        for (int i = t; i < 4096; i += 256) {
            int k = i >> 6, o = i & 63;
            tile[o * 65 + k] = __float2bfloat16(enn_W2[base + i]);
        }
        __syncthreads();
        for (int i = t; i < 4096; i += 256) {
            int o = i >> 6, k = i & 63;
            W2T[base + i] = tile[o * 65 + k];
        }
    } else {
        __shared__ float xr[4][128], ha[4][64], hb[4][64];
        int w = t >> 6, j = t & 63;
        int n = (bid - 224) * 4 + w;
        xr[w][j] = x[(size_t)n * 128 + j];
        xr[w][64 + j] = x[(size_t)n * 128 + 64 + j];
        float s = b0[j];
        #pragma unroll 8
        for (int k = 0; k < 128; ++k) s = fmaf(xr[w][k], W0[k * 64 + j], s);
        ha[w][j] = fmaxf(s, 0.f);
        s = b1[j];
        #pragma unroll 8
        for (int k = 0; k < 64; ++k) s = fmaf(ha[w][k], W1[k * 64 + j], s);
        hb[w][j] = fmaxf(s, 0.f);
        s = b2[j];
        #pragma unroll 8
        for (int k = 0; k < 64; ++k) s = fmaf(hb[w][k], W2[k * 64 + j], s);
        float val = fmaxf(s, 0.f);
        out[(size_t)n * 64 + j] = val;
        ha[w][j] = val;             // wave-private reuse (all ha reads above are done)
        agg[(size_t)n * 64 + j] = 0.f;
        float s2 = 0.f;
        #pragma unroll 8
        for (int k = 0; k < 64; ++k) s2 = fmaf(ha[w][k], b2e0[k * 64 + j], s2);
        BT[(size_t)n * 64 + j] = s2;
    }
}

// ---------------- k_edges: bucket CSR fill + cnt_dst + batch ranges ----------------
__global__ __launch_bounds__(256) void k_edges(const int* __restrict__ eidx,
        const float* __restrict__ ea, const int* __restrict__ bm,
        int* cnt_src, int* cnt_dst, int* csr_dst, float* csr_ea,
        int* bstart, int* bend) {
    int e = blockIdx.x * 256 + threadIdx.x;
    if (e < NE) {
        int s = eidx[e];
        int d = eidx[NE + e];
        int slot = atomicAdd(&cnt_src[s], 1);
        if (slot < BKT) {
            csr_dst[s * BKT + slot] = d;
            csr_ea[s * BKT + slot] = ea[e];
        }
        atomicAdd(&cnt_dst[d], 1);
    }
    if (e < NN) {
        int b = bm[e];
        atomicMin(&bstart[b], e);
        atomicMax(&bend[b], e + 1);
    }
}

// ---------------- k_fused: P-tile MFMA into LDS + register-P edge phase ----------
// Block = 8 src nodes. Phase 1: P[8n][64g][64o] via MFMA into LDS (packed bf16x2).
// After barrier each wave pulls its 2 nodes' P rows into VGPRs (preg[2][64]) ONCE,
// then overlays We1 scratch on its own (now dead) Plds region — wave-private, no
// second barrier, no shuffles. Edge loop = round-8 k_msg engine: 16 broadcast
// float4 LDS reads + 64 FMAs per edge. No P in global memory.
__global__ __launch_bounds__(256, 2) void k_fused(const float* __restrict__ out,
        const __hip_bfloat16* __restrict__ W2T_l, const float* __restrict__ BT,
        const int* __restrict__ cnt_src, const int* __restrict__ csr_dst,
        const float* __restrict__ csr_ea, const float* __restrict__ W1l,
        const float* __restrict__ b1l, float* __restrict__ agg) {
    __shared__ unsigned Plds[FN * 32 * 64];   // [n][g2][o], 2 bf16/word = 64 KB exactly
    int t = threadIdx.x, wave = t >> 6, lane = t & 63;
    int laneM = lane & 15, quad = lane >> 4;
    int n0 = blockIdx.x * FN;
    // A-fragment: A[m=laneM][k=quad*8+j] direct from global (rows 8..15 discarded)
    const float* Arow = out + (size_t)(n0 + laneM) * 64;
    f4 af0 = *(const f4*)(Arow + quad * 8);
    f4 af1 = *(const f4*)(Arow + quad * 8 + 4);
    f4 af2 = *(const f4*)(Arow + 32 + quad * 8);
    f4 af3 = *(const f4*)(Arow + 32 + quad * 8 + 4);
    short8 a0, a1;
    #pragma unroll
    for (int j = 0; j < 4; ++j) {
        a0[j] = f2bf(af0[j]); a0[4 + j] = f2bf(af1[j]);
        a1[j] = f2bf(af2[j]); a1[4 + j] = f2bf(af3[j]);
    }
    // wave w covers g in [16w, 16w+16), as 8 even/odd pairs
    #pragma unroll
    for (int gp = 0; gp < 8; ++gp) {
        int g0 = wave * 16 + gp * 2;
        const __hip_bfloat16* Bt0 = W2T_l + (size_t)g0 * 4096;   // [o][k]
        const __hip_bfloat16* Bt1 = Bt0 + 4096;
        #pragma unroll
        for (int ot = 0; ot < 4; ++ot) {
            int o0 = ot * 16;
            short8 b00 = *(const short8*)(Bt0 + (o0 + laneM) * 64 + quad * 8);
            short8 b01 = *(const short8*)(Bt0 + (o0 + laneM) * 64 + 32 + quad * 8);
            short8 b10 = *(const short8*)(Bt1 + (o0 + laneM) * 64 + quad * 8);
            short8 b11 = *(const short8*)(Bt1 + (o0 + laneM) * 64 + 32 + quad * 8);
            f4 c0 = {0.f, 0.f, 0.f, 0.f};
            f4 c1 = {0.f, 0.f, 0.f, 0.f};
            c0 = __builtin_amdgcn_mfma_f32_16x16x32_bf16(a0, b00, c0, 0, 0, 0);
            c0 = __builtin_amdgcn_mfma_f32_16x16x32_bf16(a1, b01, c0, 0, 0, 0);
            c1 = __builtin_amdgcn_mfma_f32_16x16x32_bf16(a0, b10, c1, 0, 0, 0);
            c1 = __builtin_amdgcn_mfma_f32_16x16x32_bf16(a1, b11, c1, 0, 0, 0);
            // C: col(o)=lane&15, row(node)=quad*4+r; keep nodes 0..7 only
            if (quad < 2) {
                #pragma unroll
                for (int r = 0; r < 4; ++r) {
                    int node = quad * 4 + r;
                    Plds[(node * 32 + (g0 >> 1)) * 64 + o0 + laneM] = packbf2(c0[r], c1[r]);
                }
            }
        }
    }
    __syncthreads();
    // pull both of this wave's P rows into registers (lane = o)
    float preg[2][64];
    #pragma unroll
    for (int ni = 0; ni < 2; ++ni) {
        const unsigned* Pn = Plds + (size_t)(wave * 2 + ni) * 2048;
        #pragma unroll
        for (int g2 = 0; g2 < 32; ++g2) {
            unsigned pv = Pn[g2 * 64 + lane];
            union { unsigned u; float f; } lo, hi;
            lo.u = pv << 16;            // g = 2*g2
            hi.u = pv & 0xFFFF0000u;    // g = 2*g2+1
            preg[ni][2 * g2] = lo.f;
            preg[ni][2 * g2 + 1] = hi.f;
        }
    }
    // We1 scratch overlays node 2w's region (wave-private; this wave is its only reader)
    float* wlds = (float*)(Plds + (size_t)wave * 4096);   // [32][64] floats = 8 KB
    float wcoef = W1l[lane], bcoef = b1l[lane];
    #pragma unroll
    for (int ni = 0; ni < 2; ++ni) {
        int n = n0 + wave * 2 + ni;
        int deg = cnt_src[n];
        if (deg > BKT) deg = BKT;
        float bt = BT[(size_t)n * 64 + lane];
        const int* bdst = csr_dst + n * BKT;
        const float* bea = csr_ea + n * BKT;
        for (int c0 = 0; c0 < deg; c0 += 32) {
            int cc = deg - c0; if (cc > 32) cc = 32;
            for (int si = 0; si < cc; ++si) {
                float eav = bea[c0 + si];                      // wave-uniform broadcast
                wlds[si * 64 + lane] = fmaxf(fmaf(eav, wcoef, bcoef), 0.f);  // lane = g
            }
            for (int i = 0; i < cc; ++i) {
                int dst = bdst[c0 + i];
                const float* wr = wlds + i * 64;
                float acc0 = bt, acc1 = 0.f, acc2 = 0.f, acc3 = 0.f;
                #pragma unroll
                for (int g = 0; g < 64; g += 16) {
                    float4 w0 = *(const float4*)(wr + g);
                    float4 w1 = *(const float4*)(wr + g + 4);
                    float4 w2 = *(const float4*)(wr + g + 8);
                    float4 w3 = *(const float4*)(wr + g + 12);
                    acc0 = fmaf(w0.x, preg[ni][g], acc0);
                    acc0 = fmaf(w0.y, preg[ni][g + 1], acc0);
                    acc0 = fmaf(w0.z, preg[ni][g + 2], acc0);
                    acc0 = fmaf(w0.w, preg[ni][g + 3], acc0);
                    acc1 = fmaf(w1.x, preg[ni][g + 4], acc1);
                    acc1 = fmaf(w1.y, preg[ni][g + 5], acc1);
                    acc1 = fmaf(w1.z, preg[ni][g + 6], acc1);
                    acc1 = fmaf(w1.w, preg[ni][g + 7], acc1);
                    acc2 = fmaf(w2.x, preg[ni][g + 8], acc2);
                    acc2 = fmaf(w2.y, preg[ni][g + 9], acc2);
                    acc2 = fmaf(w2.z, preg[ni][g + 10], acc2);
                    acc2 = fmaf(w2.w, preg[ni][g + 11], acc2);
                    acc3 = fmaf(w3.x, preg[ni][g + 12], acc3);
                    acc3 = fmaf(w3.y, preg[ni][g + 13], acc3);
                    acc3 = fmaf(w3.z, preg[ni][g + 14], acc3);
                    acc3 = fmaf(w3.w, preg[ni][g + 15], acc3);
                }
                float acc = (acc0 + acc1) + (acc2 + acc3);
                atomicAdd(&agg[(size_t)dst * 64 + lane], acc);  // /deg in GRU
            }
        }
    }
}

// ---------------- k_gru: conv (+deg-norm) + GRU (+BT_next +agg zero) ----------------
__global__ __launch_bounds__(256) void k_gru(const float* __restrict__ out,
        const float* __restrict__ agg, const int* __restrict__ cnt_dst,
        const float* __restrict__ rootW, const float* __restrict__ convb,
        const float* __restrict__ Wih, const float* __restrict__ Whh,
        const float* __restrict__ bih, const float* __restrict__ bhh,
        const float* __restrict__ b2next, float* __restrict__ BT,
        float* __restrict__ aggz, float* __restrict__ outn) {
    __shared__ float sh[4][64], sc[4][64];
    int t = threadIdx.x, w = t >> 6, j = t & 63;
    int n = blockIdx.x * 4 + w;
    float hj = out[(size_t)n * 64 + j];
    sh[w][j] = hj;
    int dg = cnt_dst[n];
    float invd = 1.0f / (float)(dg > 0 ? dg : 1);
    __syncthreads();
    float s = agg[(size_t)n * 64 + j] * invd + convb[j];
    #pragma unroll 8
    for (int k = 0; k < 64; ++k) s = fmaf(sh[w][k], rootW[k * 64 + j], s);
    float conv = fmaxf(s, 0.f);
    sc[w][j] = conv;
    __syncthreads();
    float gir = bih[j], giz = bih[64 + j], gin = bih[128 + j];
    float ghr = bhh[j], ghz = bhh[64 + j], ghn = bhh[128 + j];
    #pragma unroll 4
    for (int k = 0; k < 64; ++k) {
        float c = sc[w][k], h = sh[w][k];
        gir = fmaf(c, Wih[k * 192 + j], gir);
        giz = fmaf(c, Wih[k * 192 + 64 + j], giz);
        gin = fmaf(c, Wih[k * 192 + 128 + j], gin);
        ghr = fmaf(h, Whh[k * 192 + j], ghr);
        ghz = fmaf(h, Whh[k * 192 + 64 + j], ghz);
        ghn = fmaf(h, Whh[k * 192 + 128 + j], ghn);
    }
    float r = sigf(gir + ghr);
    float z = sigf(giz + ghz);
    float nnv = tanhf(gin + r * ghn);
    float val = (1.f - z) * nnv + z * hj;
    outn[(size_t)n * 64 + j] = val;
    if (b2next) {
        sh[w][j] = val;   // wave-private reuse (all sh reads above done in lockstep)
        aggz[(size_t)n * 64 + j] = 0.f;
        float s2 = 0.f;
        #pragma unroll 8
        for (int k = 0; k < 64; ++k) s2 = fmaf(sh[w][k], b2next[k * 64 + j], s2);
        BT[(size_t)n * 64 + j] = s2;
    }
}

// ---------------- Set2Set (3 steps) + post-MLP ----------------
__global__ __launch_bounds__(1024) void k_s2s_post(const float* __restrict__ out,
        const int* __restrict__ bstart, const int* __restrict__ bend,
        const float* __restrict__ Wih, const float* __restrict__ Whh,
        const float* __restrict__ bih, const float* __restrict__ bhh,
        const float* __restrict__ pW0, const float* __restrict__ pb0,
        const float* __restrict__ pW1, const float* __restrict__ pb1,
        const float* __restrict__ pW2, const float* __restrict__ pb2,
        const float* __restrict__ pW3, const float* __restrict__ pb3,
        float* __restrict__ y) {
    __shared__ float cache[192 * 65];
    __shared__ float qs[128], hh[64], cc[64], gates[256];
    __shared__ float ebuf[1024];
    __shared__ float redbuf[1024];
    __shared__ float redw[16];
    __shared__ float smax, sinv;
    __shared__ float tmp64[64];
    int t = threadIdx.x, wave = t >> 6, lane = t & 63;
    int b = blockIdx.x;
    int s0 = bstart[b], e0 = bend[b];
    int cnt = e0 - s0;
    if (cnt < 0) cnt = 0;
    if (cnt > 1024) cnt = 1024;
    int ccnt = cnt < 192 ? cnt : 192;
    for (int li = t; li < ccnt * 64; li += 1024) {
        int rowi = li >> 6, d = li & 63;
        cache[rowi * 65 + d] = out[(size_t)(s0 + rowi) * 64 + d];
    }
    int g = t & 255, seg = t >> 8;
    const float* wp;
    int kcnt;
    if (seg == 0)      { wp = Wih + g;             kcnt = 64; }
    else if (seg == 1) { wp = Wih + 64 * 256 + g;  kcnt = 64; }
    else if (seg == 2) { wp = Whh + g;             kcnt = 32; }
    else               { wp = Whh + 32 * 256 + g;  kcnt = 32; }
    float wreg[64];
    #pragma unroll
    for (int j = 0; j < 64; ++j)
        wreg[j] = (j < kcnt) ? wp[(size_t)j * 256] : 0.f;
    if (t < 128) qs[t] = 0.f;
    if (t < 64) { hh[t] = 0.f; cc[t] = 0.f; }
    __syncthreads();
    for (int step = 0; step < 3; ++step) {
        const float* vsrc = (seg == 0) ? qs : (seg == 1) ? qs + 64
                          : (seg == 2) ? hh : hh + 32;
        float partial = 0.f;
        #pragma unroll
        for (int j = 0; j < 64; ++j)
            if (j < kcnt) partial = fmaf(vsrc[j], wreg[j], partial);
        redbuf[seg * 256 + g] = partial;
        __syncthreads();
        if (t < 256)
            gates[t] = bih[t] + bhh[t] + redbuf[t] + redbuf[256 + t]
                     + redbuf[512 + t] + redbuf[768 + t];
        __syncthreads();
        if (t < 64) {
            float cn = sigf(gates[64 + t]) * cc[t] + sigf(gates[t]) * tanhf(gates[128 + t]);
            cc[t] = cn;
            hh[t] = sigf(gates[192 + t]) * tanhf(cn);
        }
        __syncthreads();
        for (int idx = t; idx < cnt; idx += 1024) {
            float s = 0.f;
            if (idx < 192) {
                const float* row = cache + idx * 65;
                #pragma unroll 8
                for (int d = 0; d < 64; ++d) s = fmaf(row[d], hh[d], s);
            } else {
                const float* row = out + (size_t)(s0 + idx) * 64;
                for (int d = 0; d < 64; ++d) s = fmaf(row[d], hh[d], s);
            }
            ebuf[idx] = s;
        }
        __syncthreads();
        float lm = (t < cnt) ? ebuf[t] : -3.0e38f;
        #pragma unroll
        for (int off = 32; off > 0; off >>= 1) lm = fmaxf(lm, __shfl_down(lm, off, 64));
        if (lane == 0) redw[wave] = lm;
        __syncthreads();
        if (t == 0) {
            float m = redw[0];
            #pragma unroll
            for (int w2 = 1; w2 < 16; ++w2) m = fmaxf(m, redw[w2]);
            smax = m;
        }
        __syncthreads();
        float m = smax;
        float av = 0.f;
        if (t < cnt) {
            av = __expf(ebuf[t] - m);
            ebuf[t] = av;
        }
        float ls = av;
        #pragma unroll
        for (int off = 32; off > 0; off >>= 1) ls += __shfl_down(ls, off, 64);
        if (lane == 0) redw[wave] = ls;
        __syncthreads();
        if (t == 0) {
            float s = 0.f;
            #pragma unroll
            for (int w2 = 0; w2 < 16; ++w2) s += redw[w2];
            sinv = (cnt > 0) ? 1.f / s : 0.f;
        }
        __syncthreads();
        float inv = sinv;
        float r = 0.f;
        for (int idx = wave; idx < cnt; idx += 16) {
            float a = ebuf[idx];
            float v = (idx < 192) ? cache[idx * 65 + lane]
                                  : out[(size_t)(s0 + idx) * 64 + lane];
            r = fmaf(a, v, r);
        }
        redbuf[wave * 64 + lane] = r;
        __syncthreads();
        if (t < 64) {
            float s = 0.f;
            #pragma unroll
            for (int w2 = 0; w2 < 16; ++w2) s += redbuf[w2 * 64 + t];
            qs[64 + t] = s * inv;
            qs[t] = hh[t];
        }
        __syncthreads();
    }
    if (t < 64) {
        float s = pb0[t];
        #pragma unroll 4
        for (int k = 0; k < 128; ++k) s = fmaf(qs[k], pW0[k * 64 + t], s);
        tmp64[t] = fmaxf(s, 0.f);
    }
    __syncthreads();
    float h1v = 0.f;
    if (t < 64) {
        float s = pb1[t];
        #pragma unroll 4
        for (int k = 0; k < 64; ++k) s = fmaf(tmp64[k], pW1[k * 64 + t], s);
        h1v = fmaxf(s, 0.f);
    }
    __syncthreads();
    if (t < 64) tmp64[t] = h1v;
    __syncthreads();
    if (t < 64) {
        float s = pb2[t];
        #pragma unroll 4
        for (int k = 0; k < 64; ++k) s = fmaf(tmp64[k], pW2[k * 64 + t], s);
        gates[t] = fmaxf(s, 0.f) * pW3[t];
    }
    __syncthreads();
    if (t == 0) {
        float yy = pb3[0];
        for (int k = 0; k < 64; ++k) yy += gates[k];
        y[b] = yy;
    }
}

// ---------------- host ----------------

extern "C" void kernel_launch(void* const* d_in, const int* in_sizes, int n_in,
                              void* d_out, int out_size, void* d_ws, size_t ws_size,
                              hipStream_t stream) {
    const float* x         = (const float*)d_in[0];
    const float* edge_attr = (const float*)d_in[1];
    const int*   edge_idx  = (const int*)d_in[2];
    const int*   batch_map = (const int*)d_in[3];
    const float* pre_W0 = (const float*)d_in[4];
    const float* pre_b0 = (const float*)d_in[5];
    const float* pre_W1 = (const float*)d_in[6];
    const float* pre_b1 = (const float*)d_in[7];
    const float* pre_W2 = (const float*)d_in[8];
    const float* pre_b2 = (const float*)d_in[9];
    const float* enn_W1 = (const float*)d_in[10];
    const float* enn_b1 = (const float*)d_in[11];
    const float* enn_W2 = (const float*)d_in[12];
    const float* enn_b2 = (const float*)d_in[13];
    const float* root_W = (const float*)d_in[14];
    const float* conv_b = (const float*)d_in[15];
    const float* gru_Wih = (const float*)d_in[16];
    const float* gru_Whh = (const float*)d_in[17];
    const float* gru_bih = (const float*)d_in[18];
    const float* gru_bhh = (const float*)d_in[19];
    const float* s2s_Wih = (const float*)d_in[20];
    const float* s2s_Whh = (const float*)d_in[21];
    const float* s2s_bih = (const float*)d_in[22];
    const float* s2s_bhh = (const float*)d_in[23];
    const float* post_W0 = (const float*)d_in[24];
    const float* post_b0 = (const float*)d_in[25];
    const float* post_W1 = (const float*)d_in[26];
    const float* post_b1 = (const float*)d_in[27];
    const float* post_W2 = (const float*)d_in[28];
    const float* post_b2 = (const float*)d_in[29];
    const float* post_W3 = (const float*)d_in[30];
    const float* post_b3 = (const float*)d_in[31];
    float* yout = (float*)d_out;

    char* wp = (char*)d_ws;
    auto take = [&](size_t bytes) -> char* {
        char* r = wp;
        wp += (bytes + 255) & ~(size_t)255;
        return r;
    };
    float* outA = (float*)take((size_t)NN * 64 * 4);
    float* outB = (float*)take((size_t)NN * 64 * 4);
    float* BT  = (float*)take((size_t)NN * 64 * 4);
    float* agg = (float*)take((size_t)NN * 64 * 4);
    __hip_bfloat16* W2T = (__hip_bfloat16*)take((size_t)3 * 64 * 4096 * 2);
    int* cnt_src  = (int*)take((size_t)NN * 4);
    int* cnt_dst  = (int*)take((size_t)NN * 4);
    int* csr_dst  = (int*)take((size_t)NN * BKT * 4);
    float* csr_ea = (float*)take((size_t)NN * BKT * 4);
    int* bstart   = (int*)take((size_t)NB * 4);
    int* bend     = (int*)take((size_t)NB * 4);

    k_setup<<<1248, 256, 0, stream>>>(x, pre_W0, pre_b0, pre_W1, pre_b1, pre_W2, pre_b2,
                                      enn_W2, enn_b2, W2T, outA, BT, agg,
                                      cnt_src, cnt_dst, bstart, bend);
    k_edges<<<NE / 256, 256, 0, stream>>>(edge_idx, edge_attr, batch_map,
                                          cnt_src, cnt_dst, csr_dst, csr_ea,
                                          bstart, bend);

    float* cur = outA;
    float* nxt = outB;
    for (int l = 0; l < 3; ++l) {
        k_fused<<<NN / FN, 256, 0, stream>>>(cur, W2T + (size_t)l * 64 * 4096, BT,
                                             cnt_src, csr_dst, csr_ea,
                                             enn_W1 + l * 64, enn_b1 + l * 64, agg);
        const float* b2next = (l < 2) ? (enn_b2 + (size_t)(l + 1) * 4096) : nullptr;
        k_gru<<<NN / 4, 256, 0, stream>>>(cur, agg, cnt_dst, root_W + l * 4096,
                                          conv_b + l * 64, gru_Wih + l * 64 * 192,
                                          gru_Whh + l * 64 * 192, gru_bih + l * 192,
                                          gru_bhh + l * 192, b2next, BT, agg, nxt);
        float* tmp = cur; cur = nxt; nxt = tmp;
    }
    k_s2s_post<<<NB, 1024, 0, stream>>>(cur, bstart, bend, s2s_Wih, s2s_Whh, s2s_bih,
                                        s2s_bhh, post_W0, post_b0, post_W1, post_b1,
                                        post_W2, post_b2, post_W3, post_b3, yout);
}

// Round 12
// 370.648 us; speedup vs baseline: 1.2366x; 1.0800x over previous
//
#include <hip/hip_runtime.h>
#include <hip/hip_bf16.h>
#include <string.h>

#define NN   4096
#define NE   32768
#define NB   32
#define BKT  64    // per-src edge bucket capacity (deg ~ Poisson(8); P(>64) ~ 1e-30)
#define PSTR 4160  // P row stride (bf16): 8KB+128B breaks HBM channel camping
#define WSTR 4160  // W2T g stride (bf16): same padding

typedef __attribute__((ext_vector_type(8))) short short8;
typedef __attribute__((ext_vector_type(4))) float f4;

__device__ __forceinline__ float sigf(float x) { return 1.0f / (1.0f + __expf(-x)); }
__device__ __forceinline__ float bf2f(short s) {
    union { unsigned u; float f; } x;
    x.u = ((unsigned)(unsigned short)s) << 16;
    return x.f;
}
__device__ __forceinline__ short f2bf(float f) {
    __hip_bfloat16 h = __float2bfloat16(f);
    short s;
    memcpy(&s, &h, sizeof(short));
    return s;
}

// ---------------- k_setup: init + W2T transpose + pre-MLP ----------------
__global__ __launch_bounds__(256) void k_setup(const float* __restrict__ x,
        const float* __restrict__ W0, const float* __restrict__ b0,
        const float* __restrict__ W1, const float* __restrict__ b1,
        const float* __restrict__ W2, const float* __restrict__ b2,
        const float* __restrict__ enn_W2, __hip_bfloat16* __restrict__ W2T,
        float* __restrict__ out, int* cnt_src, int* cnt_dst, int* bstart, int* bend) {
    int bid = blockIdx.x, t = threadIdx.x;
    if (bid < 32) {
        int i = bid * 256 + t;
        if (i < NN) cnt_src[i] = 0;
        else cnt_dst[i - NN] = 0;
        if (i < NB) { bstart[i] = 0x7FFFFFFF; bend[i] = 0; }
    } else if (bid < 224) {
        __shared__ __hip_bfloat16 tile[64 * 65];
        int tl = bid - 32;
        size_t src = (size_t)tl * 4096;
        size_t dst = (size_t)tl * WSTR;
        for (int i = t; i < 4096; i += 256) {
            int k = i >> 6, o = i & 63;
            tile[o * 65 + k] = __float2bfloat16(enn_W2[src + i]);
        }
        __syncthreads();
        for (int i = t; i < 4096; i += 256) {
            int o = i >> 6, k = i & 63;
            W2T[dst + i] = tile[o * 65 + k];
        }
    } else {
        __shared__ float xr[4][128], ha[4][64], hb[4][64];
        int w = t >> 6, j = t & 63;
        int n = (bid - 224) * 4 + w;
        xr[w][j] = x[(size_t)n * 128 + j];
        xr[w][64 + j] = x[(size_t)n * 128 + 64 + j];
        float s = b0[j];
        #pragma unroll 8
        for (int k = 0; k < 128; ++k) s = fmaf(xr[w][k], W0[k * 64 + j], s);
        ha[w][j] = fmaxf(s, 0.f);
        s = b1[j];
        #pragma unroll 8
        for (int k = 0; k < 64; ++k) s = fmaf(ha[w][k], W1[k * 64 + j], s);
        hb[w][j] = fmaxf(s, 0.f);
        s = b2[j];
        #pragma unroll 8
        for (int k = 0; k < 64; ++k) s = fmaf(hb[w][k], W2[k * 64 + j], s);
        out[(size_t)n * 64 + j] = fmaxf(s, 0.f);
    }
}

// ---------------- k_gemmPbt: MFMA P-GEMM + bterm/agg-zero (+ bucket fill on l0) ----
// gemm: no LDS/barrier, A-fragments direct from global; P stores use padded PSTR.
// blocks 0..1023: gemm job (mtile32 = b>>3 [32 rows], gchunk = b&7 [8 g's])
// blocks 1024..2047: bterm (BT = out.b2) + zero agg
// blocks 2048..2175 (layer 0 only): bucket CSR fill + cnt_dst + batch ranges
__global__ __launch_bounds__(256, 4) void k_gemmPbt(const float* __restrict__ out,
        const __hip_bfloat16* __restrict__ W2T_l, const float* __restrict__ b2l,
        __hip_bfloat16* __restrict__ P, float* __restrict__ BT, float* __restrict__ agg,
        const int* __restrict__ eidx, const float* __restrict__ ea,
        const int* __restrict__ bm, int* cnt_src, int* cnt_dst,
        int* csr_dst, float* csr_ea, int* bstart, int* bend) {
    int bid = blockIdx.x, t = threadIdx.x;
    if (bid < 1024) {
        int mtile32 = bid >> 3, gchunk = bid & 7;
        int wave = t >> 6, lane = t & 63;
        int laneM = lane & 15, quad = lane >> 4;
        int rowhalf = wave & 1, subpair = wave >> 1;
        int arow = mtile32 * 32 + rowhalf * 16 + laneM;
        const float* Arow = out + (size_t)arow * 64;
        f4 af0 = *(const f4*)(Arow + quad * 8);
        f4 af1 = *(const f4*)(Arow + quad * 8 + 4);
        f4 af2 = *(const f4*)(Arow + 32 + quad * 8);
        f4 af3 = *(const f4*)(Arow + 32 + quad * 8 + 4);
        short8 a0, a1;
        #pragma unroll
        for (int j = 0; j < 4; ++j) {
            a0[j] = f2bf(af0[j]); a0[4 + j] = f2bf(af1[j]);
            a1[j] = f2bf(af2[j]); a1[4 + j] = f2bf(af3[j]);
        }
        #pragma unroll
        for (int sp = 0; sp < 2; ++sp) {
            int o0 = (subpair * 2 + sp) * 16;
            float accs[4][8];
            #pragma unroll
            for (int gg = 0; gg < 8; ++gg) {
                const __hip_bfloat16* Bt = W2T_l + (size_t)(gchunk * 8 + gg) * WSTR;
                short8 b0v = *(const short8*)(Bt + (o0 + laneM) * 64 + quad * 8);
                short8 b1v = *(const short8*)(Bt + (o0 + laneM) * 64 + 32 + quad * 8);
                f4 acc = {0.f, 0.f, 0.f, 0.f};
                acc = __builtin_amdgcn_mfma_f32_16x16x32_bf16(a0, b0v, acc, 0, 0, 0);
                acc = __builtin_amdgcn_mfma_f32_16x16x32_bf16(a1, b1v, acc, 0, 0, 0);
                #pragma unroll
                for (int r = 0; r < 4; ++r) accs[r][gg] = acc[r];
            }
            int rowg = mtile32 * 32 + rowhalf * 16 + quad * 4;   // D row = quad*4+r
            #pragma unroll
            for (int r = 0; r < 4; ++r) {
                short8 sv;
                #pragma unroll
                for (int j = 0; j < 8; ++j)
                    sv[j] = f2bf(accs[r][j]);
                *(short8*)(P + (size_t)(rowg + r) * PSTR + gchunk * 512
                             + (o0 + laneM) * 8) = sv;
            }
        }
    } else if (bid < 2048) {
        __shared__ float sh[4][64];
        int w = t >> 6, j = t & 63;
        int n = (bid - 1024) * 4 + w;
        sh[w][j] = out[(size_t)n * 64 + j];
        agg[(size_t)n * 64 + j] = 0.f;
        __syncthreads();
        float s = 0.f;
        #pragma unroll 8
        for (int k = 0; k < 64; ++k) s = fmaf(sh[w][k], b2l[k * 64 + j], s);
        BT[(size_t)n * 64 + j] = s;
    } else {
        int e = (bid - 2048) * 256 + t;
        if (e < NE) {
            int s = eidx[e];
            int d = eidx[NE + e];
            int slot = atomicAdd(&cnt_src[s], 1);
            if (slot < BKT) {
                csr_dst[s * BKT + slot] = d;
                csr_ea[s * BKT + slot] = ea[e];
            }
            atomicAdd(&cnt_dst[d], 1);
        }
        if (e < NN) {
            int b = bm[e];
            atomicMin(&bstart[b], e);
            atomicMax(&bend[b], e + 1);
        }
    }
}

// ---------------- k_msg: per-src-wave message + scatter (bucket CSR, barrier-free) --
#define MSG_CHUNK 32
__global__ __launch_bounds__(256, 2) void k_msg(const __hip_bfloat16* __restrict__ P,
        const float* __restrict__ BT, const int* __restrict__ cnt_src,
        const int* __restrict__ csr_dst, const float* __restrict__ csr_ea,
        const float* __restrict__ W1l, const float* __restrict__ b1l,
        float* __restrict__ agg) {
    __shared__ float wlds[4][MSG_CHUNK][64];   // 32 KB, wave-private rows
    int t = threadIdx.x, wave = t >> 6, lane = t & 63;
    int n = blockIdx.x * 4 + wave;
    int deg = cnt_src[n];
    if (deg > BKT) deg = BKT;
    float w1v = W1l[lane], b1v = b1l[lane];
    float preg[64];
    const __hip_bfloat16* Pn = P + (size_t)n * PSTR + lane * 8;
    #pragma unroll
    for (int c = 0; c < 8; ++c) {
        short8 v = *(const short8*)(Pn + c * 512);
        #pragma unroll
        for (int j = 0; j < 8; ++j) preg[c * 8 + j] = bf2f(v[j]);
    }
    float bt = BT[(size_t)n * 64 + lane];
    const int* bdst = csr_dst + n * BKT;
    const float* bea = csr_ea + n * BKT;
    for (int c0 = 0; c0 < deg; c0 += MSG_CHUNK) {
        int cc = deg - c0; if (cc > MSG_CHUNK) cc = MSG_CHUNK;
        for (int si = 0; si < cc; ++si) {
            float eav = bea[c0 + si];                          // wave-uniform broadcast
            wlds[wave][si][lane] = fmaxf(fmaf(eav, w1v, b1v), 0.f);  // We1 (lane = g)
        }
        for (int i = 0; i < cc; ++i) {
            int dst = bdst[c0 + i];
            const float* wr = wlds[wave][i];
            float acc0 = bt, acc1 = 0.f, acc2 = 0.f, acc3 = 0.f;
            #pragma unroll
            for (int g = 0; g < 64; g += 16) {
                float4 w0 = *(const float4*)(wr + g);
                float4 w1 = *(const float4*)(wr + g + 4);
                float4 w2 = *(const float4*)(wr + g + 8);
                float4 w3 = *(const float4*)(wr + g + 12);
                acc0 = fmaf(w0.x, preg[g], acc0);
                acc0 = fmaf(w0.y, preg[g + 1], acc0);
                acc0 = fmaf(w0.z, preg[g + 2], acc0);
                acc0 = fmaf(w0.w, preg[g + 3], acc0);
                acc1 = fmaf(w1.x, preg[g + 4], acc1);
                acc1 = fmaf(w1.y, preg[g + 5], acc1);
                acc1 = fmaf(w1.z, preg[g + 6], acc1);
                acc1 = fmaf(w1.w, preg[g + 7], acc1);
                acc2 = fmaf(w2.x, preg[g + 8], acc2);
                acc2 = fmaf(w2.y, preg[g + 9], acc2);
                acc2 = fmaf(w2.z, preg[g + 10], acc2);
                acc2 = fmaf(w2.w, preg[g + 11], acc2);
                acc3 = fmaf(w3.x, preg[g + 12], acc3);
                acc3 = fmaf(w3.y, preg[g + 13], acc3);
                acc3 = fmaf(w3.z, preg[g + 14], acc3);
                acc3 = fmaf(w3.w, preg[g + 15], acc3);
            }
            float acc = (acc0 + acc1) + (acc2 + acc3);
            atomicAdd(&agg[(size_t)dst * 64 + lane], acc);   // un-normalized; /deg in GRU
        }
    }
}

// ---------------- k_gru: conv (+deg-normalize) + GRU ----------------
__global__ __launch_bounds__(256) void k_gru(const float* __restrict__ out,
        const float* __restrict__ agg, const int* __restrict__ cnt_dst,
        const float* __restrict__ rootW, const float* __restrict__ convb,
        const float* __restrict__ Wih, const float* __restrict__ Whh,
        const float* __restrict__ bih, const float* __restrict__ bhh,
        float* __restrict__ outn) {
    __shared__ float sh[4][64], sc[4][64];
    int t = threadIdx.x, w = t >> 6, j = t & 63;
    int n = blockIdx.x * 4 + w;
    float hj = out[(size_t)n * 64 + j];
    sh[w][j] = hj;
    int dg = cnt_dst[n];
    float invd = 1.0f / (float)(dg > 0 ? dg : 1);
    __syncthreads();
    float s = agg[(size_t)n * 64 + j] * invd + convb[j];
    #pragma unroll 8
    for (int k = 0; k < 64; ++k) s = fmaf(sh[w][k], rootW[k * 64 + j], s);
    float conv = fmaxf(s, 0.f);
    sc[w][j] = conv;
    __syncthreads();
    float gir = bih[j], giz = bih[64 + j], gin = bih[128 + j];
    float ghr = bhh[j], ghz = bhh[64 + j], ghn = bhh[128 + j];
    #pragma unroll 4
    for (int k = 0; k < 64; ++k) {
        float c = sc[w][k], h = sh[w][k];
        gir = fmaf(c, Wih[k * 192 + j], gir);
        giz = fmaf(c, Wih[k * 192 + 64 + j], giz);
        gin = fmaf(c, Wih[k * 192 + 128 + j], gin);
        ghr = fmaf(h, Whh[k * 192 + j], ghr);
        ghz = fmaf(h, Whh[k * 192 + 64 + j], ghz);
        ghn = fmaf(h, Whh[k * 192 + 128 + j], ghn);
    }
    float r = sigf(gir + ghr);
    float z = sigf(giz + ghz);
    float nn = tanhf(gin + r * ghn);
    outn[(size_t)n * 64 + j] = (1.f - z) * nn + z * hj;
}

// ---------------- Set2Set (3 steps) + post-MLP ----------------
__global__ __launch_bounds__(1024) void k_s2s_post(const float* __restrict__ out,
        const int* __restrict__ bstart, const int* __restrict__ bend,
        const float* __restrict__ Wih, const float* __restrict__ Whh,
        const float* __restrict__ bih, const float* __restrict__ bhh,
        const float* __restrict__ pW0, const float* __restrict__ pb0,
        const float* __restrict__ pW1, const float* __restrict__ pb1,
        const float* __restrict__ pW2, const float* __restrict__ pb2,
        const float* __restrict__ pW3, const float* __restrict__ pb3,
        float* __restrict__ y) {
    __shared__ float cache[192 * 65];
    __shared__ float qs[128], hh[64], cc[64], gates[256];
    __shared__ float ebuf[1024];
    __shared__ float redbuf[1024];
    __shared__ float redw[16];
    __shared__ float smax, sinv;
    __shared__ float tmp64[64];
    int t = threadIdx.x, wave = t >> 6, lane = t & 63;
    int b = blockIdx.x;
    int s0 = bstart[b], e0 = bend[b];
    int cnt = e0 - s0;
    if (cnt < 0) cnt = 0;
    if (cnt > 1024) cnt = 1024;
    int ccnt = cnt < 192 ? cnt : 192;
    for (int li = t; li < ccnt * 64; li += 1024) {
        int rowi = li >> 6, d = li & 63;
        cache[rowi * 65 + d] = out[(size_t)(s0 + rowi) * 64 + d];
    }
    int g = t & 255, seg = t >> 8;
    const float* wp;
    int kcnt;
    if (seg == 0)      { wp = Wih + g;             kcnt = 64; }
    else if (seg == 1) { wp = Wih + 64 * 256 + g;  kcnt = 64; }
    else if (seg == 2) { wp = Whh + g;             kcnt = 32; }
    else               { wp = Whh + 32 * 256 + g;  kcnt = 32; }
    float wreg[64];
    #pragma unroll
    for (int j = 0; j < 64; ++j)
        wreg[j] = (j < kcnt) ? wp[(size_t)j * 256] : 0.f;
    if (t < 128) qs[t] = 0.f;
    if (t < 64) { hh[t] = 0.f; cc[t] = 0.f; }
    __syncthreads();
    for (int step = 0; step < 3; ++step) {
        const float* vsrc = (seg == 0) ? qs : (seg == 1) ? qs + 64
                          : (seg == 2) ? hh : hh + 32;
        float partial = 0.f;
        #pragma unroll
        for (int j = 0; j < 64; ++j)
            if (j < kcnt) partial = fmaf(vsrc[j], wreg[j], partial);
        redbuf[seg * 256 + g] = partial;
        __syncthreads();
        if (t < 256)
            gates[t] = bih[t] + bhh[t] + redbuf[t] + redbuf[256 + t]
                     + redbuf[512 + t] + redbuf[768 + t];
        __syncthreads();
        if (t < 64) {
            float cn = sigf(gates[64 + t]) * cc[t] + sigf(gates[t]) * tanhf(gates[128 + t]);
            cc[t] = cn;
            hh[t] = sigf(gates[192 + t]) * tanhf(cn);
        }
        __syncthreads();
        for (int idx = t; idx < cnt; idx += 1024) {
            float s = 0.f;
            if (idx < 192) {
                const float* row = cache + idx * 65;
                #pragma unroll 8
                for (int d = 0; d < 64; ++d) s = fmaf(row[d], hh[d], s);
            } else {
                const float* row = out + (size_t)(s0 + idx) * 64;
                for (int d = 0; d < 64; ++d) s = fmaf(row[d], hh[d], s);
            }
            ebuf[idx] = s;
        }
        __syncthreads();
        float lm = (t < cnt) ? ebuf[t] : -3.0e38f;
        #pragma unroll
        for (int off = 32; off > 0; off >>= 1) lm = fmaxf(lm, __shfl_down(lm, off, 64));
        if (lane == 0) redw[wave] = lm;
        __syncthreads();
        if (t == 0) {
            float m = redw[0];
            #pragma unroll
            for (int w2 = 1; w2 < 16; ++w2) m = fmaxf(m, redw[w2]);
            smax = m;
        }
        __syncthreads();
        float m = smax;
        float av = 0.f;
        if (t < cnt) {
            av = __expf(ebuf[t] - m);
            ebuf[t] = av;
        }
        float ls = av;
        #pragma unroll
        for (int off = 32; off > 0; off >>= 1) ls += __shfl_down(ls, off, 64);
        if (lane == 0) redw[wave] = ls;
        __syncthreads();
        if (t == 0) {
            float s = 0.f;
            #pragma unroll
            for (int w2 = 0; w2 < 16; ++w2) s += redw[w2];
            sinv = (cnt > 0) ? 1.f / s : 0.f;
        }
        __syncthreads();
        float inv = sinv;
        float r = 0.f;
        for (int idx = wave; idx < cnt; idx += 16) {
            float a = ebuf[idx];
            float v = (idx < 192) ? cache[idx * 65 + lane]
                                  : out[(size_t)(s0 + idx) * 64 + lane];
            r = fmaf(a, v, r);
        }
        redbuf[wave * 64 + lane] = r;
        __syncthreads();
        if (t < 64) {
            float s = 0.f;
            #pragma unroll
            for (int w2 = 0; w2 < 16; ++w2) s += redbuf[w2 * 64 + t];
            qs[64 + t] = s * inv;
            qs[t] = hh[t];
        }
        __syncthreads();
    }
    if (t < 64) {
        float s = pb0[t];
        #pragma unroll 4
        for (int k = 0; k < 128; ++k) s = fmaf(qs[k], pW0[k * 64 + t], s);
        tmp64[t] = fmaxf(s, 0.f);
    }
    __syncthreads();
    float h1v = 0.f;
    if (t < 64) {
        float s = pb1[t];
        #pragma unroll 4
        for (int k = 0; k < 64; ++k) s = fmaf(tmp64[k], pW1[k * 64 + t], s);
        h1v = fmaxf(s, 0.f);
    }
    __syncthreads();
    if (t < 64) tmp64[t] = h1v;
    __syncthreads();
    if (t < 64) {
        float s = pb2[t];
        #pragma unroll 4
        for (int k = 0; k < 64; ++k) s = fmaf(tmp64[k], pW2[k * 64 + t], s);
        gates[t] = fmaxf(s, 0.f) * pW3[t];
    }
    __syncthreads();
    if (t == 0) {
        float yy = pb3[0];
        for (int k = 0; k < 64; ++k) yy += gates[k];
        y[b] = yy;
    }
}

// ---------------- host ----------------

extern "C" void kernel_launch(void* const* d_in, const int* in_sizes, int n_in,
                              void* d_out, int out_size, void* d_ws, size_t ws_size,
                              hipStream_t stream) {
    const float* x         = (const float*)d_in[0];
    const float* edge_attr = (const float*)d_in[1];
    const int*   edge_idx  = (const int*)d_in[2];
    const int*   batch_map = (const int*)d_in[3];
    const float* pre_W0 = (const float*)d_in[4];
    const float* pre_b0 = (const float*)d_in[5];
    const float* pre_W1 = (const float*)d_in[6];
    const float* pre_b1 = (const float*)d_in[7];
    const float* pre_W2 = (const float*)d_in[8];
    const float* pre_b2 = (const float*)d_in[9];
    const float* enn_W1 = (const float*)d_in[10];
    const float* enn_b1 = (const float*)d_in[11];
    const float* enn_W2 = (const float*)d_in[12];
    const float* enn_b2 = (const float*)d_in[13];
    const float* root_W = (const float*)d_in[14];
    const float* conv_b = (const float*)d_in[15];
    const float* gru_Wih = (const float*)d_in[16];
    const float* gru_Whh = (const float*)d_in[17];
    const float* gru_bih = (const float*)d_in[18];
    const float* gru_bhh = (const float*)d_in[19];
    const float* s2s_Wih = (const float*)d_in[20];
    const float* s2s_Whh = (const float*)d_in[21];
    const float* s2s_bih = (const float*)d_in[22];
    const float* s2s_bhh = (const float*)d_in[23];
    const float* post_W0 = (const float*)d_in[24];
    const float* post_b0 = (const float*)d_in[25];
    const float* post_W1 = (const float*)d_in[26];
    const float* post_b1 = (const float*)d_in[27];
    const float* post_W2 = (const float*)d_in[28];
    const float* post_b2 = (const float*)d_in[29];
    const float* post_W3 = (const float*)d_in[30];
    const float* post_b3 = (const float*)d_in[31];
    float* yout = (float*)d_out;

    char* wp = (char*)d_ws;
    auto take = [&](size_t bytes) -> char* {
        char* r = wp;
        wp += (bytes + 255) & ~(size_t)255;
        return r;
    };
    float* outA = (float*)take((size_t)NN * 64 * 4);
    float* outB = (float*)take((size_t)NN * 64 * 4);
    __hip_bfloat16* P = (__hip_bfloat16*)take((size_t)NN * PSTR * 2);
    float* BT  = (float*)take((size_t)NN * 64 * 4);
    float* agg = (float*)take((size_t)NN * 64 * 4);
    __hip_bfloat16* W2T = (__hip_bfloat16*)take((size_t)3 * 64 * WSTR * 2);
    int* cnt_src  = (int*)take((size_t)NN * 4);
    int* cnt_dst  = (int*)take((size_t)NN * 4);
    int* csr_dst  = (int*)take((size_t)NN * BKT * 4);
    float* csr_ea = (float*)take((size_t)NN * BKT * 4);
    int* bstart   = (int*)take((size_t)NB * 4);
    int* bend     = (int*)take((size_t)NB * 4);

    k_setup<<<1248, 256, 0, stream>>>(x, pre_W0, pre_b0, pre_W1, pre_b1, pre_W2, pre_b2,
                                      enn_W2, W2T, outA, cnt_src, cnt_dst, bstart, bend);

    float* cur = outA;
    float* nxt = outB;
    for (int l = 0; l < 3; ++l) {
        int grid = (l == 0) ? 2176 : 2048;   // layer 0 also does bucket CSR fill
        k_gemmPbt<<<grid, 256, 0, stream>>>(cur, W2T + (size_t)l * 64 * WSTR,
                                            enn_b2 + (size_t)l * 4096, P, BT, agg,
                                            edge_idx, edge_attr, batch_map,
                                            cnt_src, cnt_dst, csr_dst, csr_ea,
                                            bstart, bend);
        k_msg<<<NN / 4, 256, 0, stream>>>(P, BT, cnt_src, csr_dst, csr_ea,
                                          enn_W1 + l * 64, enn_b1 + l * 64, agg);
        k_gru<<<NN / 4, 256, 0, stream>>>(cur, agg, cnt_dst, root_W + l * 4096,
                                          conv_b + l * 64, gru_Wih + l * 64 * 192,
                                          gru_Whh + l * 64 * 192, gru_bih + l * 192,
                                          gru_bhh + l * 192, nxt);
        float* tmp = cur; cur = nxt; nxt = tmp;
    }
    k_s2s_post<<<NB, 1024, 0, stream>>>(cur, bstart, bend, s2s_Wih, s2s_Whh, s2s_bih,
                                        s2s_bhh, post_W0, post_b0, post_W1, post_b1,
                                        post_W2, post_b2, post_W3, post_b3, yout);
}